// Round 3
// baseline (272.582 us; speedup 1.0000x reference)
//
#include <hip/hip_runtime.h>

// Problem constants (B=16, C=128, H=W=64, N=4096, M=256, K=9, OUT=128)
#define NB   16
#define NC   128
#define NN   4096
#define NM   256
#define NK   9
#define NO   128

// round(linspace(0, 63, 16)) -- identical under f32 (jax) and f64 (np) linspace
__device__ __constant__ int d_grid16[16] = {0,4,8,13,17,21,25,29,34,38,42,46,50,55,59,63};

// ---------------------------------------------------------------------------
// K0: transpose w (O,C,K) -> Wr (C,K,O) for coalesced GEMM B-operand
__global__ __launch_bounds__(256) void k_wr(const float* __restrict__ w,
                                            float* __restrict__ Wr) {
    int f = blockIdx.x * 256 + threadIdx.x;         // f < 128*9*128 = 147456
    int o = f & 127;
    int k = (f >> 7) % 9;
    int c = f / 1152;
    Wr[f] = w[o * 1152 + c * 9 + k];
}

// ---------------------------------------------------------------------------
// K1: gather sample features xs[b][c][m] = x[b][c][pix(m)]
__global__ __launch_bounds__(256) void k_gather(const float* __restrict__ x,
                                                float* __restrict__ xs) {
    int bc = blockIdx.x;                            // b*128 + c
    int m  = threadIdx.x;                           // 0..255
    int pix = d_grid16[m >> 4] * 64 + d_grid16[m & 15];
    xs[bc * NM + m] = x[bc * NN + pix];
}

// ---------------------------------------------------------------------------
// K1b: m2[b][m] = sum_c xs^2 -- bit-exact np f32: sequential c, mul+add (no fma)
__global__ __launch_bounds__(256) void k_m2(const float* __restrict__ xs,
                                            float* __restrict__ m2) {
    #pragma clang fp contract(off)
    int f = blockIdx.x * 256 + threadIdx.x;         // < 4096
    int b = f >> 8, m = f & 255;
    const float* p = xs + (size_t)b * NC * NM + m;
    float a = 0.f;
    #pragma unroll 4
    for (int c = 0; c < NC; ++c) { float v = p[c * NM]; a = __fadd_rn(a, __fmul_rn(v, v)); }
    m2[f] = a;
}

// K1c: n2[b][n] = sum_c x^2 -- same exact-np recipe
__global__ __launch_bounds__(256) void k_n2(const float* __restrict__ x,
                                            float* __restrict__ n2) {
    #pragma clang fp contract(off)
    int f = blockIdx.x * 256 + threadIdx.x;         // < 65536
    int b = f >> 12, n = f & 4095;
    const float* p = x + (size_t)b * NC * NN + n;
    float a = 0.f;
    #pragma unroll 4
    for (int c = 0; c < NC; ++c) { float v = p[(size_t)c * NN]; a = __fadd_rn(a, __fmul_rn(v, v)); }
    n2[f] = a;
}

// ---------------------------------------------------------------------------
// K2: G[b][m][k][o] = sum_c xs[b][c][m] * Wr[c][k][o]   (fp32 fma - output path,
// association differences vs ref are ~1e-4 << threshold)
__global__ __launch_bounds__(256) void k_g(const float* __restrict__ xs,
                                           const float* __restrict__ Wr,
                                           float* __restrict__ G) {
    __shared__ float xsl[64 * 64];    // [cc][mm]
    __shared__ float wl[64 * 128];    // [cc][o]
    int kk = blockIdx.x, mt = blockIdx.y, b = blockIdx.z;
    int t = threadIdx.x;
    int to = t & 31, tmm = t >> 5;
    float acc[8][4] = {};
    for (int c0 = 0; c0 < NC; c0 += 64) {
        __syncthreads();
        #pragma unroll
        for (int it = 0; it < 16; ++it) {
            int f = it * 256 + t;
            int cc = f >> 6, mm = f & 63;
            xsl[f] = xs[((size_t)b * NC + c0 + cc) * NM + mt * 64 + mm];
        }
        #pragma unroll
        for (int it = 0; it < 32; ++it) {
            int f = it * 256 + t;
            int cc = f >> 7, o = f & 127;
            wl[f] = Wr[(size_t)(c0 + cc) * 1152 + kk * 128 + o];
        }
        __syncthreads();
        for (int cc = 0; cc < 64; ++cc) {
            const float4 a0 = *(const float4*)&xsl[cc * 64 + tmm * 8];
            const float4 a1 = *(const float4*)&xsl[cc * 64 + tmm * 8 + 4];
            float av[8] = {a0.x, a0.y, a0.z, a0.w, a1.x, a1.y, a1.z, a1.w};
            float2 w0 = *(const float2*)&wl[cc * 128 + 2 * to];
            float2 w1 = *(const float2*)&wl[cc * 128 + 64 + 2 * to];
            float wv[4] = {w0.x, w0.y, w1.x, w1.y};
            #pragma unroll
            for (int i = 0; i < 8; ++i)
                #pragma unroll
                for (int j = 0; j < 4; ++j)
                    acc[i][j] = fmaf(av[i], wv[j], acc[i][j]);
        }
    }
    #pragma unroll
    for (int i = 0; i < 8; ++i) {
        size_t base = (((size_t)(b * NM + mt * 64 + tmm * 8 + i) * NK + kk) << 7);
        *(float2*)&G[base + 2 * to]      = make_float2(acc[i][0], acc[i][1]);
        *(float2*)&G[base + 64 + 2 * to] = make_float2(acc[i][2], acc[i][3]);
    }
}

// ---------------------------------------------------------------------------
// K3: fused dots + top-9. Keys are BIT-EXACT to numpy f32:
//   dots: sequential c=0..127, acc = fadd(acc, fmul(x1,xs))  (no fma, no reassoc)
//   key  = fsub(fadd(n2, m2), fmul(2, dots))
// grid (128 tiles, 16 b), 256 thr; tile = 32 tokens x 256 samples.
__device__ inline unsigned long long shfl_xor_u64(unsigned long long v, int m) {
    int lo = __shfl_xor((int)(v & 0xFFFFFFFFull), m, 64);
    int hi = __shfl_xor((int)(v >> 32), m, 64);
    return ((unsigned long long)(unsigned)hi << 32) | (unsigned)lo;
}

__global__ __launch_bounds__(256) void k_sel(const float* __restrict__ x,
                                             const float* __restrict__ xs,
                                             const float* __restrict__ n2,
                                             const float* __restrict__ m2,
                                             int* __restrict__ idx) {
    #pragma clang fp contract(off)
    // staging: x1 tile [0,1024): [cc][nn] 32x32 ; xs tile [1024,9216): [cc][m] 32x256
    // phase B/C reuse sm as u32 keys [32][258] = 33024 B <= 36864 B
    __shared__ float sm[9216];
    __shared__ float m2l[256];
    __shared__ float n2l[32];
    int b = blockIdx.y, n0 = blockIdx.x * 32;
    int t = threadIdx.x;
    int tm = t & 31, tn = t >> 5;     // m-lane (8 m's), token-group (4 tokens)
    m2l[t] = m2[b * NM + t];
    if (t < 32) n2l[t] = n2[b * NN + n0 + t];
    float acc[4][8];
    #pragma unroll
    for (int i = 0; i < 4; ++i)
        #pragma unroll
        for (int j = 0; j < 8; ++j) acc[i][j] = 0.f;

    for (int c0 = 0; c0 < NC; c0 += 32) {
        __syncthreads();
        #pragma unroll
        for (int it = 0; it < 4; ++it) {
            int f = it * 256 + t;                       // 1024
            int cc = f >> 5, nn = f & 31;
            sm[f] = x[((size_t)b * NC + c0 + cc) * NN + n0 + nn];
        }
        #pragma unroll
        for (int it = 0; it < 32; ++it) {
            int f = it * 256 + t;                       // 8192
            int cc = f >> 8, m = f & 255;
            sm[1024 + f] = xs[((size_t)b * NC + c0 + cc) * NM + m];
        }
        __syncthreads();
        for (int cc = 0; cc < 32; ++cc) {               // ascending c: np order
            const float4 a4 = *(const float4*)&sm[cc * 32 + tn * 4];
            float av[4] = {a4.x, a4.y, a4.z, a4.w};
            float2 s0 = *(const float2*)&sm[1024 + cc * 256 + 2 * tm];
            float2 s1 = *(const float2*)&sm[1024 + cc * 256 + 64 + 2 * tm];
            float2 s2 = *(const float2*)&sm[1024 + cc * 256 + 128 + 2 * tm];
            float2 s3 = *(const float2*)&sm[1024 + cc * 256 + 192 + 2 * tm];
            float sv[8] = {s0.x, s0.y, s1.x, s1.y, s2.x, s2.y, s3.x, s3.y};
            #pragma unroll
            for (int i = 0; i < 4; ++i)
                #pragma unroll
                for (int j = 0; j < 8; ++j)
                    acc[i][j] = __fadd_rn(acc[i][j], __fmul_rn(av[i], sv[j]));
        }
    }
    __syncthreads();
    // ---- phase B: f32 keys (np-exact) -> monotone u32 -> LDS ----
    unsigned* keysl = (unsigned*)sm;                    // [32][258]
    int   mj[8];
    float m2v[8];
    #pragma unroll
    for (int j = 0; j < 8; ++j) { mj[j] = (j >> 1) * 64 + 2 * tm + (j & 1); m2v[j] = m2l[mj[j]]; }
    #pragma unroll
    for (int i = 0; i < 4; ++i) {
        int n = tn * 4 + i;
        float n2v = n2l[n];
        #pragma unroll
        for (int j = 0; j < 8; ++j) {
            float key = __fsub_rn(__fadd_rn(n2v, m2v[j]), __fmul_rn(2.f, acc[i][j]));
            unsigned u = __float_as_uint(key);
            u ^= (u & 0x80000000u) ? 0xFFFFFFFFu : 0x80000000u;
            keysl[n * 258 + mj[j]] = u;
        }
    }
    __syncthreads();
    // ---- phase C: per-token top-9 (8 lanes/token, packed u64 = key|m; ties -> lower m) ----
    {
        int n = t >> 3, q = t & 7;
        unsigned long long bk[9];
        #pragma unroll
        for (int j = 0; j < 9; ++j) bk[j] = ~0ull;
        for (int i = 0; i < 32; ++i) {
            int m = q + 8 * i;
            unsigned long long v = ((unsigned long long)keysl[n * 258 + m] << 32) | (unsigned)m;
            if (v < bk[8]) {
                #pragma unroll
                for (int j = 0; j < 9; ++j) {
                    unsigned long long t0 = bk[j];
                    bool c = v < t0;
                    bk[j] = c ? v : t0;
                    v     = c ? t0 : v;
                }
            }
        }
        #pragma unroll
        for (int rr = 1; rr <= 4; rr <<= 1) {
            unsigned long long pv[9];
            #pragma unroll
            for (int j = 0; j < 9; ++j) pv[j] = shfl_xor_u64(bk[j], rr);
            #pragma unroll
            for (int j = 0; j < 9; ++j) {
                unsigned long long v = pv[j];
                if (v >= bk[8]) break;                  // pv ascending: rest can't qualify
                #pragma unroll
                for (int jj = 0; jj < 9; ++jj) {
                    unsigned long long t0 = bk[jj];
                    bool c = v < t0;
                    bk[jj] = c ? v : t0;
                    v      = c ? t0 : v;
                }
            }
        }
        if (q == 0) {
            size_t base = (size_t)(b * NN + n0 + n) * NK;
            #pragma unroll
            for (int k = 0; k < 9; ++k) idx[base + k] = (int)(unsigned)(bk[k] & 0xFFFFFFFFull);
        }
    }
}

// ---------------------------------------------------------------------------
// K4: out[b][o][n] = bias[o] + sum_k G[b][idx[b,n,k]][k][o]
__global__ __launch_bounds__(256) void k_out(const float* __restrict__ G,
                                             const int* __restrict__ idx,
                                             const float* __restrict__ bias,
                                             float* __restrict__ out) {
    __shared__ float S[64 * 129];
    __shared__ int   idxl[576];
    __shared__ float biasl[128];
    int b = blockIdx.y, n0 = blockIdx.x * 64;
    int t = threadIdx.x;
    if (t < 128) biasl[t] = bias[t];
    for (int f = t; f < 576; f += 256) idxl[f] = idx[(size_t)(b * NN + n0) * NK + f];
    __syncthreads();
    int o = t & 127, half = t >> 7;
    for (int p = 0; p < 32; ++p) {
        int n = p * 2 + half;
        float a = biasl[o];
        #pragma unroll
        for (int k = 0; k < 9; ++k) {
            int m = idxl[n * 9 + k];
            a += G[(((size_t)(b * NM + m)) * NK + k) * 128 + o];
        }
        S[n * 129 + o] = a;
    }
    __syncthreads();
    int nn = t & 63, ob = t >> 6;
    for (int p = 0; p < 32; ++p) {
        int o2 = p * 4 + ob;
        out[((size_t)(b * NO + o2)) * NN + n0 + nn] = S[nn * 129 + o2];
    }
}

// ---------------------------------------------------------------------------
extern "C" void kernel_launch(void* const* d_in, const int* in_sizes, int n_in,
                              void* d_out, int out_size, void* d_ws, size_t ws_size,
                              hipStream_t stream) {
    const float* x    = (const float*)d_in[0];   // (16,128,64,64)
    const float* w    = (const float*)d_in[1];   // (128,128,9)
    const float* bias = (const float*)d_in[2];   // (128,)
    float* out = (float*)d_out;

    float* ws  = (float*)d_ws;
    float* n2  = ws;                  // 16*4096             = 65536
    float* m2  = ws + 65536;          // 16*256              = 4096
    float* xs  = ws + 69632;          // 16*128*256          = 524288
    float* Wr  = ws + 593920;         // 128*9*128           = 147456
    float* G   = ws + 741376;         // 16*256*9*128        = 4718592
    int*   idx = (int*)(ws + 5459968);// 16*4096*9           = 589824   (~24 MB total)

    k_wr    <<<dim3(576),       dim3(256), 0, stream>>>(w, Wr);
    k_gather<<<dim3(2048),      dim3(256), 0, stream>>>(x, xs);
    k_m2    <<<dim3(16),        dim3(256), 0, stream>>>(xs, m2);
    k_n2    <<<dim3(256),       dim3(256), 0, stream>>>(x, n2);
    k_g     <<<dim3(9, 4, 16),  dim3(256), 0, stream>>>(xs, Wr, G);
    k_sel   <<<dim3(128, 16),   dim3(256), 0, stream>>>(x, xs, n2, m2, idx);
    k_out   <<<dim3(64, 16),    dim3(256), 0, stream>>>(G, idx, bias, out);
}